// Round 2
// 1788.536 us; speedup vs baseline: 1.0345x; 1.0345x over previous
//
#include <hip/hip_runtime.h>
#include <math.h>

typedef unsigned short u16;
typedef unsigned int   u32;
typedef __bf16 bf16x8 __attribute__((ext_vector_type(8)));
typedef float  floatx4 __attribute__((ext_vector_type(4)));

#define DEVFN static __device__ __forceinline__

// ---- constants for this problem ----
#define Bb   8
#define Ll   9216          // 96*96
#define Cc   512
#define BL   73728         // B*L
#define HID  2048

DEVFN float bfu2f(u16 u) { union { u32 i; float f; } z; z.i = ((u32)u) << 16; return z.f; }
DEVFN u16 f2bfu(float f) {
    union { float f; u32 i; } z; z.f = f;
    u32 i = z.i;
    i += 0x7fffu + ((i >> 16) & 1u);   // RNE
    return (u16)(i >> 16);
}

DEVFN void unpack8(uint4 v, float* x) {
    x[0] = bfu2f(v.x & 0xffff); x[1] = bfu2f(v.x >> 16);
    x[2] = bfu2f(v.y & 0xffff); x[3] = bfu2f(v.y >> 16);
    x[4] = bfu2f(v.z & 0xffff); x[5] = bfu2f(v.z >> 16);
    x[6] = bfu2f(v.w & 0xffff); x[7] = bfu2f(v.w >> 16);
}
DEVFN uint4 pack8(const float* x) {
    uint4 v;
    v.x = (u32)f2bfu(x[0]) | ((u32)f2bfu(x[1]) << 16);
    v.y = (u32)f2bfu(x[2]) | ((u32)f2bfu(x[3]) << 16);
    v.z = (u32)f2bfu(x[4]) | ((u32)f2bfu(x[5]) << 16);
    v.w = (u32)f2bfu(x[6]) | ((u32)f2bfu(x[7]) << 16);
    return v;
}

DEVFN void async16(const void* g, void* l) {
    __builtin_amdgcn_global_load_lds((const __attribute__((address_space(1))) void*)g,
                                     (__attribute__((address_space(3))) void*)l, 16, 0, 0);
}

// ---------------- fp32 -> bf16 weight conversion ----------------
__global__ __launch_bounds__(256) void f2b(const float* __restrict__ s, u16* __restrict__ d, int n) {
    const int i = blockIdx.x * 256 + threadIdx.x;
    if (i < n) d[i] = f2bfu(s[i]);
}

// ---------------- LayerNorm over rows of 512: fp32 in, bf16 out ----------------
// block = 256 threads = 4 waves, one wave per row; lane handles 8 channels
__global__ __launch_bounds__(256) void ln512(const float* __restrict__ in_,
                                             const float* __restrict__ w, const float* __restrict__ b,
                                             u16* __restrict__ out) {
    const int wave = threadIdx.x >> 6, lane = threadIdx.x & 63;
    const int row = blockIdx.x * 4 + wave;
    float x[8];
    const float4* p = (const float4*)(in_ + (size_t)row * 512);
    float4 a = p[lane * 2], c = p[lane * 2 + 1];
    x[0] = a.x; x[1] = a.y; x[2] = a.z; x[3] = a.w;
    x[4] = c.x; x[5] = c.y; x[6] = c.z; x[7] = c.w;
    float s = 0.f, s2 = 0.f;
    #pragma unroll
    for (int j = 0; j < 8; ++j) { s += x[j]; s2 += x[j] * x[j]; }
    #pragma unroll
    for (int off = 32; off >= 1; off >>= 1) { s += __shfl_xor(s, off); s2 += __shfl_xor(s2, off); }
    const float m   = s * (1.f / 512.f);
    const float var = s2 * (1.f / 512.f) - m * m;
    const float r   = rsqrtf(var + 1e-5f);
    float y[8];
    const int c0 = lane * 8;
    #pragma unroll
    for (int j = 0; j < 8; ++j)
        y[j] = (x[j] - m) * r * w[c0 + j] + b[c0 + j];
    ((uint4*)(out + (size_t)row * 512))[lane] = pack8(y);
}

// ---------------- bf16 GEMM: out(M,N) = A(M,K) @ W(N,K)^T + bias ----------------
// m97 structure: 128x128 tile, BK=32, 4 waves each 64x64 (4x4 of 16x16x32 MFMA)
// EPI: 0 = store bf16; 1 = exact GELU then bf16; 2 = + resid(fp32 MxN) then store fp32
template<int EPI>
__global__ __launch_bounds__(256) void gemm_bt(
    const u16* __restrict__ A, const u16* __restrict__ W, const float* __restrict__ bias,
    const float* __restrict__ resid, void* __restrict__ out_,
    int M, int N, int K, int wbatch) {
    __shared__ __align__(16) u16 sA[128 * 32];
    __shared__ __align__(16) u16 sB[128 * 32];
    const int t = threadIdx.x;
    const int wv = t >> 6, lane = t & 63;
    const int row0 = blockIdx.y * 128, col0 = blockIdx.x * 128;
    const u16* Wb = W + (wbatch > 0 ? (size_t)(row0 / wbatch) * (size_t)N * (size_t)K : 0);
    const int wr = wv >> 1, wc = wv & 1;
    floatx4 acc[4][4] = {};
    const int rr = t >> 2, kc = t & 3;
    const int mrow = lane & 15, koff = (lane >> 4) * 8;

    for (int k0 = 0; k0 < K; k0 += 32) {
        #pragma unroll
        for (int i = 0; i < 2; ++i) {
            const u16* ga = A  + (size_t)(row0 + i * 64 + rr) * K + (k0 + kc * 8);
            const u16* gb = Wb + (size_t)(col0 + i * 64 + rr) * K + (k0 + kc * 8);
            async16(ga, (char*)sA + (i * 256 + wv * 64) * 16);
            async16(gb, (char*)sB + (i * 256 + wv * 64) * 16);
        }
        __syncthreads();
        bf16x8 af[4], bq[4];
        #pragma unroll
        for (int mi = 0; mi < 4; ++mi)
            af[mi] = *(const bf16x8*)&sA[(wr * 64 + mi * 16 + mrow) * 32 + koff];
        #pragma unroll
        for (int ni = 0; ni < 4; ++ni)
            bq[ni] = *(const bf16x8*)&sB[(wc * 64 + ni * 16 + mrow) * 32 + koff];
        #pragma unroll
        for (int mi = 0; mi < 4; ++mi)
            #pragma unroll
            for (int ni = 0; ni < 4; ++ni)
                acc[mi][ni] = __builtin_amdgcn_mfma_f32_16x16x32_bf16(af[mi], bq[ni], acc[mi][ni], 0, 0, 0);
        __syncthreads();
    }
    // epilogue: D[row=(lane>>4)*4+r][col=lane&15] per 16x16 tile (verified m89/m91 layout)
    #pragma unroll
    for (int mi = 0; mi < 4; ++mi) {
        #pragma unroll
        for (int ni = 0; ni < 4; ++ni) {
            const int col = col0 + wc * 64 + ni * 16 + mrow;
            const float bb = bias[col];
            #pragma unroll
            for (int r = 0; r < 4; ++r) {
                const int row = row0 + wr * 64 + mi * 16 + (lane >> 4) * 4 + r;
                float v2 = acc[mi][ni][r] + bb;
                if (EPI == 1) v2 = 0.5f * v2 * (1.f + erff(v2 * 0.70710678118654752f));
                if (EPI == 2) {
                    v2 += resid[(size_t)row * N + col];
                    ((float*)out_)[(size_t)row * N + col] = v2;
                } else {
                    ((u16*)out_)[(size_t)row * N + col] = f2bfu(v2);
                }
            }
        }
    }
}

// ---------------- k softmax stats over L (online max/sum), chunked ----------------
// fully-coalesced uint4 streaming. grid (128 lchunks of 72, B); block 256.
// thread t owns channels (t&63)*8..+7, walks rows (t>>6)+4i; LDS merge of the 4 row-groups.
// partials stored transposed: pmax[lc*4096 + b*512 + c] so kstats2 reads coalesced.
__global__ __launch_bounds__(256) void kstats1(const u16* __restrict__ k,
                                               float* __restrict__ pmax, float* __restrict__ psum) {
    const int lc = blockIdx.x, b = blockIdx.y;
    const int t = threadIdx.x, c8 = t & 63, rg = t >> 6;
    const u16* base = k + ((size_t)b * Ll + (size_t)lc * 72 + rg) * 512 + c8 * 8;
    float m[8], s[8];
    #pragma unroll
    for (int j = 0; j < 8; ++j) { m[j] = -1e30f; s[j] = 0.f; }
    uint4 v = *(const uint4*)base;
    for (int i = 0; i < 18; ++i) {
        uint4 vnxt;
        if (i + 1 < 18) vnxt = *(const uint4*)&base[(size_t)(i + 1) * 4 * 512];
        float x[8]; unpack8(v, x);
        #pragma unroll
        for (int j = 0; j < 8; ++j) {
            const float nm = fmaxf(m[j], x[j]);
            s[j] = s[j] * __expf(m[j] - nm) + __expf(x[j] - nm);
            m[j] = nm;
        }
        v = vnxt;
    }
    __shared__ float sm[4][512], ss[4][512];
    #pragma unroll
    for (int j = 0; j < 8; ++j) { sm[rg][c8 * 8 + j] = m[j]; ss[rg][c8 * 8 + j] = s[j]; }
    __syncthreads();
    #pragma unroll
    for (int cp = 0; cp < 2; ++cp) {
        const int c = t + cp * 256;
        float M = sm[0][c], S = ss[0][c];
        #pragma unroll
        for (int r = 1; r < 4; ++r) {
            const float m2 = sm[r][c], s2 = ss[r][c];
            const float nm = fmaxf(M, m2);
            S = S * __expf(M - nm) + s2 * __expf(m2 - nm);
            M = nm;
        }
        pmax[(size_t)lc * 4096 + b * 512 + c] = M;
        psum[(size_t)lc * 4096 + b * 512 + c] = S;
    }
}

__global__ __launch_bounds__(256) void kstats2(const float* __restrict__ pmax, const float* __restrict__ psum,
                                               float* __restrict__ kmax, float* __restrict__ ksum) {
    const int id = blockIdx.x * 256 + threadIdx.x;   // b*512 + c, 4096 total
    float M = -1e30f, S = 0.f;
    for (int lc = 0; lc < 128; ++lc) {
        const float m2 = pmax[(size_t)lc * 4096 + id], s2 = psum[(size_t)lc * 4096 + id];
        const float nm = fmaxf(M, m2);
        S = S * __expf(M - nm) + s2 * __expf(m2 - nm);
        M = nm;
    }
    kmax[id] = M; ksum[id] = S;
}

__global__ __launch_bounds__(256) void zerof(float* __restrict__ p) {
    p[blockIdx.x * 256 + threadIdx.x] = 0.f;
}

// ---------------- context: ctxraw[b,h,dk,dv] = sum_l exp(k - kmax) * val ----------------
// grid (16 lchunks of 576, 8 heads, B) = 1024 blocks (4/CU). Per step stage 32 rows
// of exp'd k and raw val into LDS with uint4 loads; software-pipelined next-step loads;
// thread owns 4x4 (dk,dv) tile; atomics merge chunks.
__global__ __launch_bounds__(256, 4) void ctxk(const u16* __restrict__ k, const u16* __restrict__ val,
                                               const float* __restrict__ kmax, float* __restrict__ ctx) {
    const int lc = blockIdx.x, h = blockIdx.y, b = blockIdx.z;
    const int t = threadIdx.x;
    const int lrow = t >> 3, lcol = t & 7;   // loader: 32 rows x (8 lanes x 8ch of the head)
    const int dkt = t >> 4, dvt = t & 15;    // compute mapping
    __shared__ __align__(16) float ke[32][64];
    __shared__ __align__(16) float ve[32][64];
    float acc[4][4] = {};
    const size_t rowbase = ((size_t)b * Ll + (size_t)lc * 576) * 512 + h * 64 + lcol * 8;
    float km[8];
    {
        const float* kmb = kmax + b * 512 + h * 64 + lcol * 8;
        #pragma unroll
        for (int j = 0; j < 8; ++j) km[j] = kmb[j];
    }
    uint4 kv = *(const uint4*)&k[rowbase + (size_t)lrow * 512];
    uint4 vv = *(const uint4*)&val[rowbase + (size_t)lrow * 512];
    for (int l0 = 0; l0 < 576; l0 += 32) {
        float kf[8], vf[8];
        unpack8(kv, kf); unpack8(vv, vf);
        __syncthreads();                       // previous step's LDS reads complete
        #pragma unroll
        for (int j = 0; j < 8; ++j) ke[lrow][lcol * 8 + j] = __expf(kf[j] - km[j]);
        #pragma unroll
        for (int j = 0; j < 8; ++j) ve[lrow][lcol * 8 + j] = vf[j];
        __syncthreads();
        if (l0 + 32 < 576) {                   // issue next-step loads: latency hides under compute
            kv = *(const uint4*)&k[rowbase + (size_t)(l0 + 32 + lrow) * 512];
            vv = *(const uint4*)&val[rowbase + (size_t)(l0 + 32 + lrow) * 512];
        }
        #pragma unroll
        for (int li2 = 0; li2 < 32; ++li2) {
            const float4 kk = *(const float4*)&ke[li2][dkt * 4];
            const float4 vv2 = *(const float4*)&ve[li2][dvt * 4];
            acc[0][0] += kk.x * vv2.x; acc[0][1] += kk.x * vv2.y; acc[0][2] += kk.x * vv2.z; acc[0][3] += kk.x * vv2.w;
            acc[1][0] += kk.y * vv2.x; acc[1][1] += kk.y * vv2.y; acc[1][2] += kk.y * vv2.z; acc[1][3] += kk.y * vv2.w;
            acc[2][0] += kk.z * vv2.x; acc[2][1] += kk.z * vv2.y; acc[2][2] += kk.z * vv2.z; acc[2][3] += kk.z * vv2.w;
            acc[3][0] += kk.w * vv2.x; acc[3][1] += kk.w * vv2.y; acc[3][2] += kk.w * vv2.z; acc[3][3] += kk.w * vv2.w;
        }
    }
    float* cp = ctx + (((size_t)(b * 8 + h) * 64 + dkt * 4) * 64 + dvt * 4);
    #pragma unroll
    for (int i = 0; i < 4; ++i)
        #pragma unroll
        for (int j = 0; j < 4; ++j)
            atomicAdd(&cp[(size_t)i * 64 + j], acc[i][j]);
}

// ---------------- q softmax over each 64-channel head segment, in place (bf16) ----------------
__global__ __launch_bounds__(256) void qsm(u16* __restrict__ q) {
    const size_t seg = (size_t)blockIdx.x * 256 + threadIdx.x;  // 589824 total
    u16* p = q + seg * 64;
    float x[64];
    #pragma unroll
    for (int i = 0; i < 8; ++i) { uint4 v = ((const uint4*)p)[i]; unpack8(v, x + i * 8); }
    float m = x[0];
    #pragma unroll
    for (int i = 1; i < 64; ++i) m = fmaxf(m, x[i]);
    float s = 0.f;
    #pragma unroll
    for (int i = 0; i < 64; ++i) { x[i] = __expf(x[i] - m); s += x[i]; }
    const float inv = 1.f / s;
    #pragma unroll
    for (int i = 0; i < 64; ++i) x[i] *= inv;
    #pragma unroll
    for (int i = 0; i < 8; ++i) ((uint4*)p)[i] = pack8(x + i * 8);
}

// ---------------- Weff[b,co,ck] = (1/ksum[b,ck]) * sum_dv wr[co, h*64+dv] * ctx[b,h,dk,dv] ----------------
__global__ __launch_bounds__(256) void weffk(const float* __restrict__ ctx, const float* __restrict__ wr,
                                             const float* __restrict__ ksum, u16* __restrict__ weff) {
    const int b = blockIdx.y;
    const int idx = blockIdx.x * 256 + threadIdx.x;  // 262144 per b
    const int co = idx >> 9, ck = idx & 511;
    const int h = ck >> 6, dk = ck & 63;
    const float* wrp = wr + (size_t)co * 512 + h * 64;
    const float* cp = ctx + ((size_t)(b * 8 + h) * 64 + dk) * 64;
    float s = 0.f;
    #pragma unroll 8
    for (int dv = 0; dv < 64; ++dv) s += wrp[dv] * cp[dv];
    s /= ksum[b * 512 + ck];
    weff[((size_t)b * 512 + co) * 512 + ck] = f2bfu(s);
}

// ---------------- assemble x1: transpose (l,co)->flat co*L+l, add xn and raw x ----------------
// grid (8 co-tiles, 144 l-tiles, B); x1 fp32 flat (B, L*C)
__global__ __launch_bounds__(256) void assemble(const u16* __restrict__ attnCT, const u16* __restrict__ xn,
                                                const float* __restrict__ x, float* __restrict__ x1) {
    const int ct = blockIdx.x, lt = blockIdx.y, b = blockIdx.z;
    __shared__ float tile[64][65];
    const int t = threadIdx.x, j = t & 63, i0 = t >> 6;
    const size_t base = ((size_t)b * Ll + (size_t)lt * 64) * 512 + ct * 64;
    #pragma unroll
    for (int ii = 0; ii < 16; ++ii) {
        const int i = i0 + ii * 4;  // l index
        tile[i][j] = bfu2f(attnCT[base + (size_t)i * 512 + j]) + bfu2f(xn[base + (size_t)i * 512 + j]);
    }
    __syncthreads();
    const size_t bb = (size_t)b * Ll * 512;
    #pragma unroll
    for (int ii = 0; ii < 16; ++ii) {
        const int co = i0 + ii * 4;
        const size_t n = (size_t)(ct * 64 + co) * Ll + (size_t)lt * 64 + j;
        x1[bb + n] = tile[j][co] + x[bb + n];
    }
}

extern "C" void kernel_launch(void* const* d_in, const int* in_sizes, int n_in,
                              void* d_out, int out_size, void* d_ws, size_t ws_size,
                              hipStream_t stream) {
    (void)in_sizes; (void)n_in; (void)out_size; (void)ws_size;
    const float* x    = (const float*)d_in[0];
    const float* v    = (const float*)d_in[1];
    const float* ln1w = (const float*)d_in[4];
    const float* ln1b = (const float*)d_in[5];
    const float* lnvw = (const float*)d_in[6];
    const float* lnvb = (const float*)d_in[7];
    const float* ln2w = (const float*)d_in[8];
    const float* ln2b = (const float*)d_in[9];
    const float* wq   = (const float*)d_in[10]; const float* bq_ = (const float*)d_in[11];
    const float* wk   = (const float*)d_in[12]; const float* bk_ = (const float*)d_in[13];
    const float* wv_  = (const float*)d_in[14]; const float* bv_ = (const float*)d_in[15];
    const float* wr_  = (const float*)d_in[16]; const float* br_ = (const float*)d_in[17];
    const float* f1w  = (const float*)d_in[18]; const float* f1b = (const float*)d_in[19];
    const float* f2w  = (const float*)d_in[20]; const float* f2b_ = (const float*)d_in[21];
    float* out = (float*)d_out;

    char* ws = (char*)d_ws;
    // buffer layout (bytes); reuse: vn->attnCT, q->hin, kk->fc1-out chunk
    u16*   xn   = (u16*)(ws);                        // 75497472
    u16*   vn   = (u16*)(ws + 75497472ull);          // 75497472 (later attnCT)
    u16*   q    = (u16*)(ws + 150994944ull);         // 75497472 (later hin)
    u16*   kk   = (u16*)(ws + 226492416ull);         // 75497472 (later fc1 out chunk)
    u16*   val  = (u16*)(ws + 301989888ull);         // 75497472
    float* x1   = (float*)(ws + 377487360ull);       // 150994944
    float* kmax = (float*)(ws + 528482304ull);       // 16384
    float* ksum = (float*)(ws + 528498688ull);       // 16384
    float* ctx  = (float*)(ws + 528777216ull);       // 1048576
    u16*   weff = (u16*)(ws + 529825792ull);         // 4194304
    u16*   bwq  = (u16*)(ws + 534020096ull);         // 524288
    u16*   bwk  = (u16*)(ws + 534544384ull);         // 524288
    u16*   bwv  = (u16*)(ws + 535068672ull);         // 524288
    u16*   bf1  = (u16*)(ws + 535592960ull);         // 2097152
    u16*   bf2  = (u16*)(ws + 537690112ull);         // 2097152 -> end 539787264 (~515 MiB)
    // pmax/psum (4096 x 128 fp32 = 2 MiB each) live in the x1 region: dead before
    // assemble writes x1 at step 8 (consumed by kstats2 at step 3).
    float* pmax = x1;
    float* psum = x1 + 524288;

    // 0. convert GEMM weights fp32 -> bf16
    f2b<<<1024, 256, 0, stream>>>(wq,  bwq, 262144);
    f2b<<<1024, 256, 0, stream>>>(wk,  bwk, 262144);
    f2b<<<1024, 256, 0, stream>>>(wv_, bwv, 262144);
    f2b<<<4096, 256, 0, stream>>>(f1w, bf1, 1048576);
    f2b<<<4096, 256, 0, stream>>>(f2w, bf2, 1048576);
    // 1. LayerNorms of x and v (fp32 in, bf16 out)
    ln512<<<18432, 256, 0, stream>>>(x, ln1w, ln1b, xn);
    ln512<<<18432, 256, 0, stream>>>(v, lnvw, lnvb, vn);
    // 2. projections
    gemm_bt<0><<<dim3(4, 576), 256, 0, stream>>>(xn, bwq, bq_, nullptr, q,   BL, 512, 512, 0);
    gemm_bt<0><<<dim3(4, 576), 256, 0, stream>>>(vn, bwk, bk_, nullptr, kk,  BL, 512, 512, 0);
    gemm_bt<0><<<dim3(4, 576), 256, 0, stream>>>(vn, bwv, bv_, nullptr, val, BL, 512, 512, 0);
    // 3. k softmax stats (over spatial L per channel), coalesced streaming
    kstats1<<<dim3(128, 8), 256, 0, stream>>>(kk, pmax, psum);
    kstats2<<<16, 256, 0, stream>>>(pmax, psum, kmax, ksum);
    // 4. context (raw, exp-shifted; 1/ksum folded into Weff)
    zerof<<<1024, 256, 0, stream>>>(ctx);
    ctxk<<<dim3(16, 8, 8), 256, 0, stream>>>(kk, val, kmax, ctx);
    // 5. q softmax per head segment (in place)
    qsm<<<2304, 256, 0, stream>>>(q);
    // 6. Weff = wr @ blockdiag(context) scaled by 1/ksum
    weffk<<<dim3(1024, 8), 256, 0, stream>>>(ctx, wr_, ksum, weff);
    // 7. attnCT[b,l,co] = q_sm[b,l,:] . Weff[b,co,:] + br  (per-batch weights)
    gemm_bt<0><<<dim3(4, 576), 256, 0, stream>>>(q, weff, br_, nullptr, vn /*attnCT*/, BL, 512, 512, Ll);
    // 8. x1 = reinterpret(reproj + xn^T) + x   (fp32)
    assemble<<<dim3(8, 144, 8), 256, 0, stream>>>(vn, xn, x, x1);
    // 9. LN2 -> hin (bf16, stored in q buffer)
    ln512<<<18432, 256, 0, stream>>>(x1, ln2w, ln2b, q /*hin*/);
    // 10. MLP in 4 row-chunks of 18432; fc2 fuses +x1 residual and writes fp32 d_out
    for (int c2 = 0; c2 < 4; ++c2) {
        const size_t m0 = (size_t)c2 * 18432;
        gemm_bt<1><<<dim3(16, 144), 256, 0, stream>>>(q + m0 * 512, bf1, f1b, nullptr, kk,
                                                      18432, HID, 512, 0);
        gemm_bt<2><<<dim3(4, 144), 256, 0, stream>>>(kk, bf2, f2b_, x1 + m0 * 512, out + m0 * 512,
                                                     18432, 512, HID, 0);
    }
}

// Round 4
// 1640.737 us; speedup vs baseline: 1.1277x; 1.0901x over previous
//
#include <hip/hip_runtime.h>
#include <math.h>

typedef unsigned short u16;
typedef unsigned int   u32;
typedef __bf16 bf16x8 __attribute__((ext_vector_type(8)));
typedef float  floatx4 __attribute__((ext_vector_type(4)));

#define DEVFN static __device__ __forceinline__

// ---- constants for this problem ----
#define Bb   8
#define Ll   9216          // 96*96
#define Cc   512
#define BL   73728         // B*L
#define HID  2048

DEVFN float bfu2f(u16 u) { union { u32 i; float f; } z; z.i = ((u32)u) << 16; return z.f; }
DEVFN u16 f2bfu(float f) {
    union { float f; u32 i; } z; z.f = f;
    u32 i = z.i;
    i += 0x7fffu + ((i >> 16) & 1u);   // RNE
    return (u16)(i >> 16);
}

DEVFN void unpack8(uint4 v, float* x) {
    x[0] = bfu2f(v.x & 0xffff); x[1] = bfu2f(v.x >> 16);
    x[2] = bfu2f(v.y & 0xffff); x[3] = bfu2f(v.y >> 16);
    x[4] = bfu2f(v.z & 0xffff); x[5] = bfu2f(v.z >> 16);
    x[6] = bfu2f(v.w & 0xffff); x[7] = bfu2f(v.w >> 16);
}
DEVFN uint4 pack8(const float* x) {
    uint4 v;
    v.x = (u32)f2bfu(x[0]) | ((u32)f2bfu(x[1]) << 16);
    v.y = (u32)f2bfu(x[2]) | ((u32)f2bfu(x[3]) << 16);
    v.z = (u32)f2bfu(x[4]) | ((u32)f2bfu(x[5]) << 16);
    v.w = (u32)f2bfu(x[6]) | ((u32)f2bfu(x[7]) << 16);
    return v;
}

DEVFN void async16(const void* g, void* l) {
    __builtin_amdgcn_global_load_lds((const __attribute__((address_space(1))) void*)g,
                                     (__attribute__((address_space(3))) void*)l, 16, 0, 0);
}

// ---------------- fp32 -> bf16 weight conversion ----------------
__global__ __launch_bounds__(256) void f2b(const float* __restrict__ s, u16* __restrict__ d, int n) {
    const int i = blockIdx.x * 256 + threadIdx.x;
    if (i < n) d[i] = f2bfu(s[i]);
}

// ---------------- LayerNorm over rows of 512: fp32 in, bf16 out ----------------
// block = 256 threads = 4 waves, one wave per row; lane handles 8 channels
__global__ __launch_bounds__(256) void ln512(const float* __restrict__ in_,
                                             const float* __restrict__ w, const float* __restrict__ b,
                                             u16* __restrict__ out) {
    const int wave = threadIdx.x >> 6, lane = threadIdx.x & 63;
    const int row = blockIdx.x * 4 + wave;
    float x[8];
    const float4* p = (const float4*)(in_ + (size_t)row * 512);
    float4 a = p[lane * 2], c = p[lane * 2 + 1];
    x[0] = a.x; x[1] = a.y; x[2] = a.z; x[3] = a.w;
    x[4] = c.x; x[5] = c.y; x[6] = c.z; x[7] = c.w;
    float s = 0.f, s2 = 0.f;
    #pragma unroll
    for (int j = 0; j < 8; ++j) { s += x[j]; s2 += x[j] * x[j]; }
    #pragma unroll
    for (int off = 32; off >= 1; off >>= 1) { s += __shfl_xor(s, off); s2 += __shfl_xor(s2, off); }
    const float m   = s * (1.f / 512.f);
    const float var = s2 * (1.f / 512.f) - m * m;
    const float r   = rsqrtf(var + 1e-5f);
    float y[8];
    const int c0 = lane * 8;
    #pragma unroll
    for (int j = 0; j < 8; ++j)
        y[j] = (x[j] - m) * r * w[c0 + j] + b[c0 + j];
    ((uint4*)(out + (size_t)row * 512))[lane] = pack8(y);
}

// ---------------- bf16 GEMM: out(M,N) = A(M,K) @ W(N,K)^T + bias ----------------
// m97 structure: 128x128 tile, BK=32, 4 waves each 64x64 (4x4 of 16x16x32 MFMA)
// EPI: 0 = store bf16; 1 = exact GELU then bf16; 2 = + resid(fp32 MxN) then store fp32
// EPI: 3 = dual-output kv projection: cols 0..511 -> out_ (bias), cols 512..1023 -> out2_ (bias2),
//          both bf16 with row stride 512 (N must be 1024)
template<int EPI>
__global__ __launch_bounds__(256) void gemm_bt(
    const u16* __restrict__ A, const u16* __restrict__ W, const float* __restrict__ bias,
    const float* __restrict__ resid, void* __restrict__ out_,
    const float* __restrict__ bias2, void* __restrict__ out2_,
    int M, int N, int K, int wbatch) {
    __shared__ __align__(16) u16 sA[128 * 32];
    __shared__ __align__(16) u16 sB[128 * 32];
    const int t = threadIdx.x;
    const int wv = t >> 6, lane = t & 63;
    const int row0 = blockIdx.y * 128, col0 = blockIdx.x * 128;
    const u16* Wb = W + (wbatch > 0 ? (size_t)(row0 / wbatch) * (size_t)N * (size_t)K : 0);
    const int wr = wv >> 1, wc = wv & 1;
    floatx4 acc[4][4] = {};
    const int rr = t >> 2, kc = t & 3;
    const int mrow = lane & 15, koff = (lane >> 4) * 8;

    for (int k0 = 0; k0 < K; k0 += 32) {
        #pragma unroll
        for (int i = 0; i < 2; ++i) {
            const u16* ga = A  + (size_t)(row0 + i * 64 + rr) * K + (k0 + kc * 8);
            const u16* gb = Wb + (size_t)(col0 + i * 64 + rr) * K + (k0 + kc * 8);
            async16(ga, (char*)sA + (i * 256 + wv * 64) * 16);
            async16(gb, (char*)sB + (i * 256 + wv * 64) * 16);
        }
        __syncthreads();
        bf16x8 af[4], bq[4];
        #pragma unroll
        for (int mi = 0; mi < 4; ++mi)
            af[mi] = *(const bf16x8*)&sA[(wr * 64 + mi * 16 + mrow) * 32 + koff];
        #pragma unroll
        for (int ni = 0; ni < 4; ++ni)
            bq[ni] = *(const bf16x8*)&sB[(wc * 64 + ni * 16 + mrow) * 32 + koff];
        #pragma unroll
        for (int mi = 0; mi < 4; ++mi)
            #pragma unroll
            for (int ni = 0; ni < 4; ++ni)
                acc[mi][ni] = __builtin_amdgcn_mfma_f32_16x16x32_bf16(af[mi], bq[ni], acc[mi][ni], 0, 0, 0);
        __syncthreads();
    }
    // epilogue: D[row=(lane>>4)*4+r][col=lane&15] per 16x16 tile (verified m89/m91 layout)
    // EPI==3: block-uniform dual-output select (tile width 128 divides the 512 split)
    u16* dst3 = nullptr; const float* bs3 = bias;
    if (EPI == 3) {
        dst3 = (col0 < 512) ? (u16*)out_ : (u16*)out2_;
        bs3  = (col0 < 512) ? bias : bias2;
    }
    #pragma unroll
    for (int mi = 0; mi < 4; ++mi) {
        #pragma unroll
        for (int ni = 0; ni < 4; ++ni) {
            const int col = col0 + wc * 64 + ni * 16 + mrow;
            const float bb = (EPI == 3) ? bs3[col & 511] : bias[col];
            #pragma unroll
            for (int r = 0; r < 4; ++r) {
                const int row = row0 + wr * 64 + mi * 16 + (lane >> 4) * 4 + r;
                float v2 = acc[mi][ni][r] + bb;
                if (EPI == 1) v2 = 0.5f * v2 * (1.f + erff(v2 * 0.70710678118654752f));
                if (EPI == 2) {
                    v2 += resid[(size_t)row * N + col];
                    ((float*)out_)[(size_t)row * N + col] = v2;
                } else if (EPI == 3) {
                    dst3[(size_t)row * 512 + (col & 511)] = f2bfu(v2);
                } else {
                    ((u16*)out_)[(size_t)row * N + col] = f2bfu(v2);
                }
            }
        }
    }
}

// ---------------- k softmax stats over L (online max/sum), chunked ----------------
// fully-coalesced uint4 streaming. grid (128 lchunks of 72, B); block 256.
// thread t owns channels (t&63)*8..+7, walks rows (t>>6)+4i; LDS merge of the 4 row-groups.
// partials stored transposed: pmax[lc*4096 + b*512 + c] so kstats2 reads coalesced.
__global__ __launch_bounds__(256) void kstats1(const u16* __restrict__ k,
                                               float* __restrict__ pmax, float* __restrict__ psum) {
    const int lc = blockIdx.x, b = blockIdx.y;
    const int t = threadIdx.x, c8 = t & 63, rg = t >> 6;
    const u16* base = k + ((size_t)b * Ll + (size_t)lc * 72 + rg) * 512 + c8 * 8;
    float m[8], s[8];
    #pragma unroll
    for (int j = 0; j < 8; ++j) { m[j] = -1e30f; s[j] = 0.f; }
    uint4 v = *(const uint4*)base;
    for (int i = 0; i < 18; ++i) {
        uint4 vnxt;
        if (i + 1 < 18) vnxt = *(const uint4*)&base[(size_t)(i + 1) * 4 * 512];
        float x[8]; unpack8(v, x);
        #pragma unroll
        for (int j = 0; j < 8; ++j) {
            const float nm = fmaxf(m[j], x[j]);
            s[j] = s[j] * __expf(m[j] - nm) + __expf(x[j] - nm);
            m[j] = nm;
        }
        v = vnxt;
    }
    __shared__ float sm[4][512], ss[4][512];
    #pragma unroll
    for (int j = 0; j < 8; ++j) { sm[rg][c8 * 8 + j] = m[j]; ss[rg][c8 * 8 + j] = s[j]; }
    __syncthreads();
    #pragma unroll
    for (int cp = 0; cp < 2; ++cp) {
        const int c = t + cp * 256;
        float M = sm[0][c], S = ss[0][c];
        #pragma unroll
        for (int r = 1; r < 4; ++r) {
            const float m2 = sm[r][c], s2 = ss[r][c];
            const float nm = fmaxf(M, m2);
            S = S * __expf(M - nm) + s2 * __expf(m2 - nm);
            M = nm;
        }
        pmax[(size_t)lc * 4096 + b * 512 + c] = M;
        psum[(size_t)lc * 4096 + b * 512 + c] = S;
    }
}

__global__ __launch_bounds__(256) void kstats2(const float* __restrict__ pmax, const float* __restrict__ psum,
                                               float* __restrict__ kmax, float* __restrict__ ksum) {
    const int id = blockIdx.x * 256 + threadIdx.x;   // b*512 + c, 4096 total
    float M = -1e30f, S = 0.f;
    for (int lc = 0; lc < 128; ++lc) {
        const float m2 = pmax[(size_t)lc * 4096 + id], s2 = psum[(size_t)lc * 4096 + id];
        const float nm = fmaxf(M, m2);
        S = S * __expf(M - nm) + s2 * __expf(m2 - nm);
        M = nm;
    }
    kmax[id] = M; ksum[id] = S;
}

__global__ __launch_bounds__(256) void zerof(float* __restrict__ p) {
    p[blockIdx.x * 256 + threadIdx.x] = 0.f;
}

// ---------------- context: ctxraw[b,h,dk,dv] = sum_l exp(k - kmax) * val ----------------
// grid (16 lchunks of 576, 8 heads, B) = 1024 blocks (4/CU). Per step stage 32 rows
// of exp'd k and raw val into LDS with uint4 loads; software-pipelined next-step loads;
// thread owns 4x4 (dk,dv) tile; atomics merge chunks.
__global__ __launch_bounds__(256, 4) void ctxk(const u16* __restrict__ k, const u16* __restrict__ val,
                                               const float* __restrict__ kmax, float* __restrict__ ctx) {
    const int lc = blockIdx.x, h = blockIdx.y, b = blockIdx.z;
    const int t = threadIdx.x;
    const int lrow = t >> 3, lcol = t & 7;   // loader: 32 rows x (8 lanes x 8ch of the head)
    const int dkt = t >> 4, dvt = t & 15;    // compute mapping
    __shared__ __align__(16) float ke[32][64];
    __shared__ __align__(16) float ve[32][64];
    float acc[4][4] = {};
    const size_t rowbase = ((size_t)b * Ll + (size_t)lc * 576) * 512 + h * 64 + lcol * 8;
    float km[8];
    {
        const float* kmb = kmax + b * 512 + h * 64 + lcol * 8;
        #pragma unroll
        for (int j = 0; j < 8; ++j) km[j] = kmb[j];
    }
    uint4 kv = *(const uint4*)&k[rowbase + (size_t)lrow * 512];
    uint4 vv = *(const uint4*)&val[rowbase + (size_t)lrow * 512];
    for (int l0 = 0; l0 < 576; l0 += 32) {
        float kf[8], vf[8];
        unpack8(kv, kf); unpack8(vv, vf);
        __syncthreads();                       // previous step's LDS reads complete
        #pragma unroll
        for (int j = 0; j < 8; ++j) ke[lrow][lcol * 8 + j] = __expf(kf[j] - km[j]);
        #pragma unroll
        for (int j = 0; j < 8; ++j) ve[lrow][lcol * 8 + j] = vf[j];
        __syncthreads();
        if (l0 + 32 < 576) {                   // issue next-step loads: latency hides under compute
            kv = *(const uint4*)&k[rowbase + (size_t)(l0 + 32 + lrow) * 512];
            vv = *(const uint4*)&val[rowbase + (size_t)(l0 + 32 + lrow) * 512];
        }
        #pragma unroll
        for (int li2 = 0; li2 < 32; ++li2) {
            const float4 kk = *(const float4*)&ke[li2][dkt * 4];
            const float4 vv2 = *(const float4*)&ve[li2][dvt * 4];
            acc[0][0] += kk.x * vv2.x; acc[0][1] += kk.x * vv2.y; acc[0][2] += kk.x * vv2.z; acc[0][3] += kk.x * vv2.w;
            acc[1][0] += kk.y * vv2.x; acc[1][1] += kk.y * vv2.y; acc[1][2] += kk.y * vv2.z; acc[1][3] += kk.y * vv2.w;
            acc[2][0] += kk.z * vv2.x; acc[2][1] += kk.z * vv2.y; acc[2][2] += kk.z * vv2.z; acc[2][3] += kk.z * vv2.w;
            acc[3][0] += kk.w * vv2.x; acc[3][1] += kk.w * vv2.y; acc[3][2] += kk.w * vv2.z; acc[3][3] += kk.w * vv2.w;
        }
    }
    float* cp = ctx + (((size_t)(b * 8 + h) * 64 + dkt * 4) * 64 + dvt * 4);
    #pragma unroll
    for (int i = 0; i < 4; ++i)
        #pragma unroll
        for (int j = 0; j < 4; ++j)
            atomicAdd(&cp[(size_t)i * 64 + j], acc[i][j]);
}

// ---------------- q softmax over each 64-channel head segment, in place (bf16) ----------------
__global__ __launch_bounds__(256) void qsm(u16* __restrict__ q) {
    const size_t seg = (size_t)blockIdx.x * 256 + threadIdx.x;  // 589824 total
    u16* p = q + seg * 64;
    float x[64];
    #pragma unroll
    for (int i = 0; i < 8; ++i) { uint4 v = ((const uint4*)p)[i]; unpack8(v, x + i * 8); }
    float m = x[0];
    #pragma unroll
    for (int i = 1; i < 64; ++i) m = fmaxf(m, x[i]);
    float s = 0.f;
    #pragma unroll
    for (int i = 0; i < 64; ++i) { x[i] = __expf(x[i] - m); s += x[i]; }
    const float inv = 1.f / s;
    #pragma unroll
    for (int i = 0; i < 64; ++i) x[i] *= inv;
    #pragma unroll
    for (int i = 0; i < 8; ++i) ((uint4*)p)[i] = pack8(x + i * 8);
}

// ---------------- Weff[b,co,ck] = (1/ksum[b,ck]) * sum_dv wr[co, h*64+dv] * ctx[b,h,dk,dv] ----------------
__global__ __launch_bounds__(256) void weffk(const float* __restrict__ ctx, const float* __restrict__ wr,
                                             const float* __restrict__ ksum, u16* __restrict__ weff) {
    const int b = blockIdx.y;
    const int idx = blockIdx.x * 256 + threadIdx.x;  // 262144 per b
    const int co = idx >> 9, ck = idx & 511;
    const int h = ck >> 6, dk = ck & 63;
    const float* wrp = wr + (size_t)co * 512 + h * 64;
    const float* cp = ctx + ((size_t)(b * 8 + h) * 64 + dk) * 64;
    float s = 0.f;
    #pragma unroll 8
    for (int dv = 0; dv < 64; ++dv) s += wrp[dv] * cp[dv];
    s /= ksum[b * 512 + ck];
    weff[((size_t)b * 512 + co) * 512 + ck] = f2bfu(s);
}

// ---------------- assemble x1: transpose (l,co)->flat co*L+l, add xn and raw x ----------------
// grid (8 co-tiles, 144 l-tiles, B); x1 fp32 flat (B, L*C)
__global__ __launch_bounds__(256) void assemble(const u16* __restrict__ attnCT, const u16* __restrict__ xn,
                                                const float* __restrict__ x, float* __restrict__ x1) {
    const int ct = blockIdx.x, lt = blockIdx.y, b = blockIdx.z;
    __shared__ float tile[64][65];
    const int t = threadIdx.x, j = t & 63, i0 = t >> 6;
    const size_t base = ((size_t)b * Ll + (size_t)lt * 64) * 512 + ct * 64;
    #pragma unroll
    for (int ii = 0; ii < 16; ++ii) {
        const int i = i0 + ii * 4;  // l index
        tile[i][j] = bfu2f(attnCT[base + (size_t)i * 512 + j]) + bfu2f(xn[base + (size_t)i * 512 + j]);
    }
    __syncthreads();
    const size_t bb = (size_t)b * Ll * 512;
    #pragma unroll
    for (int ii = 0; ii < 16; ++ii) {
        const int co = i0 + ii * 4;
        const size_t n = (size_t)(ct * 64 + co) * Ll + (size_t)lt * 64 + j;
        x1[bb + n] = tile[j][co] + x[bb + n];
    }
}

extern "C" void kernel_launch(void* const* d_in, const int* in_sizes, int n_in,
                              void* d_out, int out_size, void* d_ws, size_t ws_size,
                              hipStream_t stream) {
    (void)in_sizes; (void)n_in; (void)out_size; (void)ws_size;
    const float* x    = (const float*)d_in[0];
    const float* v    = (const float*)d_in[1];
    const float* ln1w = (const float*)d_in[4];
    const float* ln1b = (const float*)d_in[5];
    const float* lnvw = (const float*)d_in[6];
    const float* lnvb = (const float*)d_in[7];
    const float* ln2w = (const float*)d_in[8];
    const float* ln2b = (const float*)d_in[9];
    const float* wq   = (const float*)d_in[10]; const float* bq_ = (const float*)d_in[11];
    const float* wk   = (const float*)d_in[12]; const float* bk_ = (const float*)d_in[13];
    const float* wv_  = (const float*)d_in[14]; const float* bv_ = (const float*)d_in[15];
    const float* wr_  = (const float*)d_in[16]; const float* br_ = (const float*)d_in[17];
    const float* f1w  = (const float*)d_in[18]; const float* f1b = (const float*)d_in[19];
    const float* f2w  = (const float*)d_in[20]; const float* f2b_ = (const float*)d_in[21];
    float* out = (float*)d_out;

    char* ws = (char*)d_ws;
    // buffer layout (bytes); reuse: vn->attnCT, val->hin, [xn..kk)->hbuf
    u16*   xn   = (u16*)(ws);                        // 75497472
    u16*   vn   = (u16*)(ws + 75497472ull);          // 75497472 (later attnCT)
    u16*   q    = (u16*)(ws + 150994944ull);         // 75497472
    u16*   kk   = (u16*)(ws + 226492416ull);         // 75497472
    u16*   val  = (u16*)(ws + 301989888ull);         // 75497472 (later hin)
    float* x1   = (float*)(ws + 377487360ull);       // 150994944
    float* kmax = (float*)(ws + 528482304ull);       // 16384
    float* ksum = (float*)(ws + 528498688ull);       // 16384
    float* ctx  = (float*)(ws + 528777216ull);       // 1048576
    u16*   weff = (u16*)(ws + 529825792ull);         // 4194304
    u16*   bwq  = (u16*)(ws + 534020096ull);         // 524288
    u16*   bwk  = (u16*)(ws + 534544384ull);         // 524288 \ contiguous: acts as combined
    u16*   bwv  = (u16*)(ws + 535068672ull);         // 524288 /  [wk;wv] (1024x512) weight
    u16*   bf1  = (u16*)(ws + 535592960ull);         // 2097152
    u16*   bf2  = (u16*)(ws + 537690112ull);         // 2097152 -> end 539787264 (~515 MiB)
    // pmax/psum (2 MiB each) alias the x1 region: consumed (kstats2, step 3) before
    // assemble writes x1 (step 8).
    float* pmax = x1;
    float* psum = x1 + 524288;
    // hbuf (full fc1 output, 73728 x 2048 bf16 = 301989888 B) aliases [xn,vn,q,kk):
    // all four are dead once LN2 (step 9) has run; hin lives in the val slot (dead
    // after ctxk, step 4). Zero workspace growth.
    u16*   hbuf = (u16*)(ws);
    u16*   hin  = val;

    // 0. convert GEMM weights fp32 -> bf16
    f2b<<<1024, 256, 0, stream>>>(wq,  bwq, 262144);
    f2b<<<1024, 256, 0, stream>>>(wk,  bwk, 262144);
    f2b<<<1024, 256, 0, stream>>>(wv_, bwv, 262144);
    f2b<<<4096, 256, 0, stream>>>(f1w, bf1, 1048576);
    f2b<<<4096, 256, 0, stream>>>(f2w, bf2, 1048576);
    // 1. LayerNorms of x and v (fp32 in, bf16 out)
    ln512<<<18432, 256, 0, stream>>>(x, ln1w, ln1b, xn);
    ln512<<<18432, 256, 0, stream>>>(v, lnvw, lnvb, vn);
    // 2. projections: q alone; k+val fused (shared A-read, combined 1024-row weight)
    gemm_bt<0><<<dim3(4, 576), 256, 0, stream>>>(xn, bwq, bq_, nullptr, q, nullptr, nullptr,
                                                 BL, 512, 512, 0);
    gemm_bt<3><<<dim3(8, 576), 256, 0, stream>>>(vn, bwk, bk_, nullptr, kk, bv_, val,
                                                 BL, 1024, 512, 0);
    // 3. k softmax stats (over spatial L per channel), coalesced streaming
    kstats1<<<dim3(128, 8), 256, 0, stream>>>(kk, pmax, psum);
    kstats2<<<16, 256, 0, stream>>>(pmax, psum, kmax, ksum);
    // 4. context (raw, exp-shifted; 1/ksum folded into Weff)
    zerof<<<1024, 256, 0, stream>>>(ctx);
    ctxk<<<dim3(16, 8, 8), 256, 0, stream>>>(kk, val, kmax, ctx);
    // 5. q softmax per head segment (in place)
    qsm<<<2304, 256, 0, stream>>>(q);
    // 6. Weff = wr @ blockdiag(context) scaled by 1/ksum
    weffk<<<dim3(1024, 8), 256, 0, stream>>>(ctx, wr_, ksum, weff);
    // 7. attnCT[b,l,co] = q_sm[b,l,:] . Weff[b,co,:] + br  (per-batch weights)
    gemm_bt<0><<<dim3(4, 576), 256, 0, stream>>>(q, weff, br_, nullptr, vn /*attnCT*/,
                                                 nullptr, nullptr, BL, 512, 512, Ll);
    // 8. x1 = reinterpret(reproj + xn^T) + x   (fp32)
    assemble<<<dim3(8, 144, 8), 256, 0, stream>>>(vn, xn, x, x1);
    // 9. LN2 -> hin (bf16, in the dead val slot)
    ln512<<<18432, 256, 0, stream>>>(x1, ln2w, ln2b, hin);
    // 10. MLP, single full-size launches (occupancy: fc2 576->2304 blocks)
    gemm_bt<1><<<dim3(16, 576), 256, 0, stream>>>(hin, bf1, f1b, nullptr, hbuf,
                                                  nullptr, nullptr, BL, HID, 512, 0);
    gemm_bt<2><<<dim3(4, 576), 256, 0, stream>>>(hbuf, bf2, f2b_, x1, out,
                                                 nullptr, nullptr, BL, 512, HID, 0);
}